// Round 4
// baseline (479.566 us; speedup 1.0000x reference)
//
#include <hip/hip_runtime.h>
#include <hip/hip_bf16.h>
#include <math.h>

#define N_TOK 4096
#define DIM   1024
#define NEXP  8
#define IDIM  2048
#define TWOI  4096
#define CAP   1280

#define W1_BLOCKS (64 * 16 * NEXP)   // 8192
#define W2_BLOCKS (16 * 32 * NEXP)   // 4096
#define TRANS_TOTAL (W1_BLOCKS + W2_BLOCKS)
#define ROUTER_BLOCKS (N_TOK / 4)

using short8  = __attribute__((ext_vector_type(8))) short;
using floatx4 = __attribute__((ext_vector_type(4))) float;

__device__ __forceinline__ unsigned short f2b(float f) {
  __hip_bfloat16 h = __float2bfloat16(f);
  return *reinterpret_cast<unsigned short*>(&h);
}

// async global->LDS, 16B per lane. LDS dst = wave-uniform base + lane*16.
__device__ __forceinline__ void async16(const unsigned short* g, unsigned short* l) {
  __builtin_amdgcn_global_load_lds(
      (const __attribute__((address_space(1))) unsigned int*)g,
      (__attribute__((address_space(3))) unsigned int*)l,
      16, 0, 0);
}

// ---------------- prologue: weight transpose+convert AND router, one launch ----------------
// trans part: W1 [E][DIM][TWOI] f32 -> w1t [E][TWOI][DIM] bf16; W2 likewise.
// router part: logits (fp64 acc), top-2 softmax, x->bf16, out zero-init.
__global__ __launch_bounds__(256) void prologue_kernel(const float* __restrict__ W1,
                                                       const float* __restrict__ W2,
                                                       unsigned short* __restrict__ w1t,
                                                       unsigned short* __restrict__ w2t,
                                                       const float* __restrict__ x,
                                                       const float* __restrict__ Wg,
                                                       unsigned short* __restrict__ xb,
                                                       float* __restrict__ out,
                                                       int* __restrict__ top_i,
                                                       float* __restrict__ gates) {
  __shared__ __align__(16) float smem_f[NEXP * DIM];   // 32 KB, overlaid usage
  int bid = blockIdx.x;
  int tid = threadIdx.x;

  if (bid < TRANS_TOTAL) {
    float (*tile)[65] = reinterpret_cast<float (*)[65]>(smem_f);
    const float* s; unsigned short* d; int R, C, r0, c0;
    if (bid < W1_BLOCKS) {
      int e = bid >> 10;
      int t = bid & 1023;
      R = DIM; C = TWOI;
      r0 = (t & 15) * 64;
      c0 = (t >> 4) * 64;
      s = W1 + (size_t)e * R * C;
      d = w1t + (size_t)e * R * C;
    } else {
      int b2 = bid - W1_BLOCKS;
      int e = b2 >> 9;
      int t = b2 & 511;
      R = IDIM; C = DIM;
      r0 = (t & 31) * 64;
      c0 = (t >> 5) * 64;
      s = W2 + (size_t)e * R * C;
      d = w2t + (size_t)e * R * C;
    }
    int tr = tid >> 4, tc = (tid & 15) * 4;
#pragma unroll
    for (int i = 0; i < 4; i++) {
      float4 v = *reinterpret_cast<const float4*>(&s[(size_t)(r0 + tr + i * 16) * C + c0 + tc]);
      tile[tr + i * 16][tc]     = v.x;
      tile[tr + i * 16][tc + 1] = v.y;
      tile[tr + i * 16][tc + 2] = v.z;
      tile[tr + i * 16][tc + 3] = v.w;
    }
    __syncthreads();
#pragma unroll
    for (int j = 0; j < 4; j++) {
      int c = (tid >> 4) + j * 16;
      int r4 = (tid & 15) * 4;
      ushort4 o;
      o.x = f2b(tile[r4][c]);
      o.y = f2b(tile[r4 + 1][c]);
      o.z = f2b(tile[r4 + 2][c]);
      o.w = f2b(tile[r4 + 3][c]);
      *reinterpret_cast<ushort4*>(&d[(size_t)(c0 + c) * R + r0 + r4]) = o;
    }
  } else {
    int rb = bid - TRANS_TOTAL;
    float* wg = smem_f;
    for (int i = tid * 4; i < NEXP * DIM; i += 256 * 4) {
      *reinterpret_cast<float4*>(wg + i) = *reinterpret_cast<const float4*>(Wg + i);
    }
    __syncthreads();
    int wave = tid >> 6, lane = tid & 63;
    int t = rb * 4 + wave;
    const float* xr = x + (size_t)t * DIM;
    unsigned short* xbr = xb + (size_t)t * DIM;
    float* outr = out + (size_t)t * DIM;
    double acc[NEXP];
#pragma unroll
    for (int e = 0; e < NEXP; e++) acc[e] = 0.0;
    for (int i = lane; i < DIM; i += 64) {
      float xf = xr[i];
      xbr[i] = f2b(xf);
      outr[i] = 0.0f;
      double xv = (double)xf;
#pragma unroll
      for (int e = 0; e < NEXP; e++) acc[e] += xv * (double)wg[e * DIM + i];
    }
#pragma unroll
    for (int e = 0; e < NEXP; e++) {
#pragma unroll
      for (int m = 1; m < 64; m <<= 1) acc[e] += __shfl_xor(acc[e], m, 64);
    }
    if (lane == 0) {
      int i0 = 0; double v0 = acc[0];
      for (int e = 1; e < NEXP; e++) { if (acc[e] > v0) { v0 = acc[e]; i0 = e; } }
      int i1 = -1; double v1 = -1e300;
      for (int e = 0; e < NEXP; e++) { if (e != i0 && acc[e] > v1) { v1 = acc[e]; i1 = e; } }
      double e1 = exp(v1 - v0);
      float g0 = (float)(1.0 / (1.0 + e1));
      float g1 = (float)(e1 / (1.0 + e1));
      top_i[t * 2] = i0; top_i[t * 2 + 1] = i1;
      gates[t * 2] = g0; gates[t * 2 + 1] = g1;
    }
  }
}

// ---------------- capacity scan (deterministic, token-major slot order) ----------------
__global__ __launch_bounds__(1024) void scan_kernel(const int* __restrict__ top_i,
                                                    const float* __restrict__ gates,
                                                    int* __restrict__ rowtok,
                                                    float* __restrict__ rowgate,
                                                    int* __restrict__ cnt) {
  __shared__ int hist[NEXP][1024];
  int t = threadIdx.x;
  int s0 = t * 8;
  int eloc[8];
  int c[NEXP];
#pragma unroll
  for (int e = 0; e < NEXP; e++) c[e] = 0;
#pragma unroll
  for (int j = 0; j < 8; j++) { int e = top_i[s0 + j]; eloc[j] = e; c[e]++; }
#pragma unroll
  for (int e = 0; e < NEXP; e++) hist[e][t] = c[e];
  __syncthreads();
  for (int step = 1; step < 1024; step <<= 1) {
    int tmp[NEXP];
#pragma unroll
    for (int e = 0; e < NEXP; e++) tmp[e] = (t >= step) ? hist[e][t - step] : 0;
    __syncthreads();
#pragma unroll
    for (int e = 0; e < NEXP; e++) hist[e][t] += tmp[e];
    __syncthreads();
  }
  int base[NEXP];
#pragma unroll
  for (int e = 0; e < NEXP; e++) base[e] = hist[e][t] - c[e];
  if (t < NEXP) {
    int tot = hist[t][1023];
    cnt[t] = tot < CAP ? tot : CAP;
  }
#pragma unroll
  for (int j = 0; j < 8; j++) {
    int s = s0 + j;
    int e = eloc[j];
    int pos = base[e]++;
    if (pos < CAP) {
      rowtok[e * CAP + pos] = s >> 1;
      rowgate[e * CAP + pos] = gates[s];
    }
  }
}

// ---------------- GEMM1 + GLU ----------------
// Block tile: 128m x 64n of H (both inp & gate halves). Per-wave 64x32 dual acc.
__global__ __launch_bounds__(256, 4) void gemm1_kernel(const unsigned short* __restrict__ xb,
                                                       const unsigned short* __restrict__ w1t,
                                                       const int* __restrict__ rowtok,
                                                       const int* __restrict__ cnt,
                                                       unsigned short* __restrict__ H) {
  int e  = blockIdx.z;
  int m0 = blockIdx.y * 128;
  int i0 = blockIdx.x * 64;
  int cnte = cnt[e];
  if (m0 >= cnte) return;

  __shared__ __align__(16) unsigned short As[128 * 32];
  __shared__ __align__(16) unsigned short Bi[64 * 32];
  __shared__ __align__(16) unsigned short Bg[64 * 32];

  int tid  = threadIdx.x;
  int lane = tid & 63;
  int wave = tid >> 6;

  int srA0 = wave * 32 + (lane >> 2);
  int srA1 = srA0 + 16;
  int srB  = wave * 16 + (lane >> 2);
  int sk   = (lane & 3) * 8;

  int ma0 = m0 + srA0, ma1 = m0 + srA1;
  int tok0 = (ma0 < cnte) ? rowtok[e * CAP + ma0] : 0;
  int tok1 = (ma1 < cnte) ? rowtok[e * CAP + ma1] : 0;

  const unsigned short* w1e = w1t + (size_t)e * TWOI * DIM;
  const unsigned short* gA0 = xb + (size_t)tok0 * DIM + sk;
  const unsigned short* gA1 = xb + (size_t)tok1 * DIM + sk;
  const unsigned short* gBi = w1e + (size_t)(i0 + srB) * DIM + sk;
  const unsigned short* gBg = w1e + (size_t)(i0 + srB + IDIM) * DIM + sk;

  unsigned short* lA0 = As + (wave * 2 + 0) * 512;
  unsigned short* lA1 = As + (wave * 2 + 1) * 512;
  unsigned short* lBi = Bi + wave * 512;
  unsigned short* lBg = Bg + wave * 512;

  int lane16 = lane & 15;
  int quad   = lane >> 4;
  int wm = (wave & 1) * 64;
  int wn = (wave >> 1) * 32;

  floatx4 acc_i[4][2], acc_g[4][2];
#pragma unroll
  for (int i = 0; i < 4; i++)
#pragma unroll
    for (int j = 0; j < 2; j++) {
      acc_i[i][j] = (floatx4){0.f, 0.f, 0.f, 0.f};
      acc_g[i][j] = (floatx4){0.f, 0.f, 0.f, 0.f};
    }

  for (int k0 = 0; k0 < DIM; k0 += 32) {
    __syncthreads();
    async16(gA0 + k0, lA0);
    async16(gA1 + k0, lA1);
    async16(gBi + k0, lBi);
    async16(gBg + k0, lBg);
    __syncthreads();

    short8 a[4];
#pragma unroll
    for (int i = 0; i < 4; i++)
      a[i] = *(const short8*)&As[(wm + i * 16 + lane16) * 32 + quad * 8];
#pragma unroll
    for (int j = 0; j < 2; j++) {
      short8 bi = *(const short8*)&Bi[(wn + j * 16 + lane16) * 32 + quad * 8];
#pragma unroll
      for (int i = 0; i < 4; i++)
        acc_i[i][j] = __builtin_amdgcn_mfma_f32_16x16x32_bf16(a[i], bi, acc_i[i][j], 0, 0, 0);
      short8 bg = *(const short8*)&Bg[(wn + j * 16 + lane16) * 32 + quad * 8];
#pragma unroll
      for (int i = 0; i < 4; i++)
        acc_g[i][j] = __builtin_amdgcn_mfma_f32_16x16x32_bf16(a[i], bg, acc_g[i][j], 0, 0, 0);
    }
  }

  unsigned short* He = H + (size_t)e * CAP * IDIM;
#pragma unroll
  for (int i = 0; i < 4; i++) {
#pragma unroll
    for (int r = 0; r < 4; r++) {
      int m = m0 + wm + i * 16 + quad * 4 + r;
#pragma unroll
      for (int j = 0; j < 2; j++) {
        int n = i0 + wn + j * 16 + lane16;
        float vi = acc_i[i][j][r];
        float vg = acc_g[i][j][r];
        float h = 0.5f * vi * (1.0f + erff(vi * 0.70710678118654752f)) * vg;
        He[(size_t)m * IDIM + n] = f2b(h);
      }
    }
  }
}

// ---------------- GEMM2 + scatter-combine ----------------
// Block tile: 128m x 64n. Epilogue scatters gate-weighted rows into out via atomicAdd.
__global__ __launch_bounds__(256, 4) void gemm2_kernel(const unsigned short* __restrict__ H,
                                                       const unsigned short* __restrict__ w2t,
                                                       const int* __restrict__ cnt,
                                                       const int* __restrict__ rowtok,
                                                       const float* __restrict__ rowgate,
                                                       float* __restrict__ out) {
  int e  = blockIdx.z;
  int m0 = blockIdx.y * 128;
  int n0 = blockIdx.x * 64;
  int cnte = cnt[e];
  if (m0 >= cnte) return;

  __shared__ __align__(16) unsigned short As[128 * 32];
  __shared__ __align__(16) unsigned short Bs[64 * 32];

  int tid  = threadIdx.x;
  int lane = tid & 63;
  int wave = tid >> 6;

  int sr0 = wave * 32 + (lane >> 2);
  int sr1 = sr0 + 16;
  int srB = wave * 16 + (lane >> 2);
  int sk  = (lane & 3) * 8;

  const unsigned short* He  = H + (size_t)e * CAP * IDIM;
  const unsigned short* w2e = w2t + (size_t)e * DIM * IDIM;
  const unsigned short* gA0 = He + (size_t)(m0 + sr0) * IDIM + sk;
  const unsigned short* gA1 = He + (size_t)(m0 + sr1) * IDIM + sk;
  const unsigned short* gB  = w2e + (size_t)(n0 + srB) * IDIM + sk;

  unsigned short* lA0 = As + (wave * 2 + 0) * 512;
  unsigned short* lA1 = As + (wave * 2 + 1) * 512;
  unsigned short* lB  = Bs + wave * 512;

  int lane16 = lane & 15;
  int quad   = lane >> 4;
  int wm = (wave & 1) * 64;
  int wn = (wave >> 1) * 32;

  floatx4 acc[4][2];
#pragma unroll
  for (int i = 0; i < 4; i++)
#pragma unroll
    for (int j = 0; j < 2; j++) acc[i][j] = (floatx4){0.f, 0.f, 0.f, 0.f};

  for (int k0 = 0; k0 < IDIM; k0 += 32) {
    __syncthreads();
    async16(gA0 + k0, lA0);
    async16(gA1 + k0, lA1);
    async16(gB + k0, lB);
    __syncthreads();

    short8 a[4];
#pragma unroll
    for (int i = 0; i < 4; i++)
      a[i] = *(const short8*)&As[(wm + i * 16 + lane16) * 32 + quad * 8];
#pragma unroll
    for (int j = 0; j < 2; j++) {
      short8 b = *(const short8*)&Bs[(wn + j * 16 + lane16) * 32 + quad * 8];
#pragma unroll
      for (int i = 0; i < 4; i++)
        acc[i][j] = __builtin_amdgcn_mfma_f32_16x16x32_bf16(a[i], b, acc[i][j], 0, 0, 0);
    }
  }

#pragma unroll
  for (int i = 0; i < 4; i++) {
#pragma unroll
    for (int r = 0; r < 4; r++) {
      int m = m0 + wm + i * 16 + quad * 4 + r;
      if (m < cnte) {
        int tok = rowtok[e * CAP + m];
        float g = rowgate[e * CAP + m];
        float* orow = out + (size_t)tok * DIM;
#pragma unroll
        for (int j = 0; j < 2; j++) {
          int n = n0 + wn + j * 16 + lane16;
          atomicAdd(orow + n, g * acc[i][j][r]);
        }
      }
    }
  }
}

// ---------------- launch ----------------
extern "C" void kernel_launch(void* const* d_in, const int* in_sizes, int n_in,
                              void* d_out, int out_size, void* d_ws, size_t ws_size,
                              hipStream_t stream) {
  const float* x  = (const float*)d_in[0];
  const float* Wg = (const float*)d_in[1];
  const float* W1 = (const float*)d_in[2];
  const float* W2 = (const float*)d_in[3];
  float* out = (float*)d_out;

  char* ws = (char*)d_ws;
  size_t off = 0;
  auto alloc = [&](size_t bytes) -> void* {
    void* p = ws + off;
    off = (off + bytes + 255) & ~(size_t)255;
    return p;
  };
  int*   top_i   = (int*)alloc((size_t)N_TOK * 2 * sizeof(int));
  float* gates   = (float*)alloc((size_t)N_TOK * 2 * sizeof(float));
  int*   rowtok  = (int*)alloc((size_t)NEXP * CAP * sizeof(int));
  float* rowgate = (float*)alloc((size_t)NEXP * CAP * sizeof(float));
  int*   cnt     = (int*)alloc((size_t)NEXP * sizeof(int));
  unsigned short* xb  = (unsigned short*)alloc((size_t)N_TOK * DIM * 2);
  unsigned short* w1t = (unsigned short*)alloc((size_t)NEXP * TWOI * DIM * 2);
  unsigned short* w2t = (unsigned short*)alloc((size_t)NEXP * DIM * IDIM * 2);
  unsigned short* Hb  = (unsigned short*)alloc((size_t)NEXP * CAP * IDIM * 2);
  if (off > ws_size) return;

  hipLaunchKernelGGL(prologue_kernel, dim3(TRANS_TOTAL + ROUTER_BLOCKS), dim3(256), 0, stream,
                     W1, W2, w1t, w2t, x, Wg, xb, out, top_i, gates);
  hipLaunchKernelGGL(scan_kernel, dim3(1), dim3(1024), 0, stream,
                     top_i, gates, rowtok, rowgate, cnt);
  hipLaunchKernelGGL(gemm1_kernel, dim3(IDIM / 64, CAP / 128, NEXP), dim3(256), 0, stream,
                     xb, w1t, rowtok, cnt, Hb);
  hipLaunchKernelGGL(gemm2_kernel, dim3(DIM / 64, CAP / 128, NEXP), dim3(256), 0, stream,
                     Hb, w2t, cnt, rowtok, rowgate, out);
}

// Round 5
// 471.534 us; speedup vs baseline: 1.0170x; 1.0170x over previous
//
#include <hip/hip_runtime.h>
#include <hip/hip_bf16.h>
#include <math.h>

#define N_TOK 4096
#define DIM   1024
#define NEXP  8
#define IDIM  2048
#define TWOI  4096
#define CAP   1280

#define W1_BLOCKS (64 * 16 * NEXP)   // 8192 transpose tiles for W1
#define W2_BLOCKS (16 * 32 * NEXP)   // 4096 transpose tiles for W2
#define ROUTER_BLOCKS (N_TOK / 4)    // 1024

// gemm1 grid: x=32 n-tiles, y=10 m-tiles, z = 8 experts + 13 trans planes (320 blocks each)
#define G1X 32
#define G1Y 10
#define G1_TRANS_Z ((W2_BLOCKS + G1X * G1Y - 1) / (G1X * G1Y))  // 13

using short8  = __attribute__((ext_vector_type(8))) short;
using floatx4 = __attribute__((ext_vector_type(4))) float;

__device__ __forceinline__ unsigned short f2b(float f) {
  __hip_bfloat16 h = __float2bfloat16(f);
  return *reinterpret_cast<unsigned short*>(&h);
}

// async global->LDS, 16B per lane. LDS dst = wave-uniform base + lane*16.
__device__ __forceinline__ void async16(const unsigned short* g, unsigned short* l) {
  __builtin_amdgcn_global_load_lds(
      (const __attribute__((address_space(1))) unsigned int*)g,
      (__attribute__((address_space(3))) unsigned int*)l,
      16, 0, 0);
}

// ---------------- prologue: W1 transpose+convert AND router ----------------
__global__ __launch_bounds__(256) void prologue_kernel(const float* __restrict__ W1,
                                                       unsigned short* __restrict__ w1t,
                                                       const float* __restrict__ x,
                                                       const float* __restrict__ Wg,
                                                       unsigned short* __restrict__ xb,
                                                       float* __restrict__ out,
                                                       int* __restrict__ top_i,
                                                       float* __restrict__ gates) {
  __shared__ __align__(16) float smem_f[NEXP * DIM];   // 32 KB, overlaid
  int bid = blockIdx.x;
  int tid = threadIdx.x;

  if (bid < W1_BLOCKS) {
    float (*tile)[65] = reinterpret_cast<float (*)[65]>(smem_f);
    int e = bid >> 10;
    int t = bid & 1023;
    const int R = DIM, C = TWOI;
    int r0 = (t & 15) * 64;
    int c0 = (t >> 4) * 64;
    const float* s = W1 + (size_t)e * R * C;
    unsigned short* d = w1t + (size_t)e * R * C;
    int tr = tid >> 4, tc = (tid & 15) * 4;
#pragma unroll
    for (int i = 0; i < 4; i++) {
      float4 v = *reinterpret_cast<const float4*>(&s[(size_t)(r0 + tr + i * 16) * C + c0 + tc]);
      tile[tr + i * 16][tc]     = v.x;
      tile[tr + i * 16][tc + 1] = v.y;
      tile[tr + i * 16][tc + 2] = v.z;
      tile[tr + i * 16][tc + 3] = v.w;
    }
    __syncthreads();
#pragma unroll
    for (int j = 0; j < 4; j++) {
      int c = (tid >> 4) + j * 16;
      int r4 = (tid & 15) * 4;
      ushort4 o;
      o.x = f2b(tile[r4][c]);
      o.y = f2b(tile[r4 + 1][c]);
      o.z = f2b(tile[r4 + 2][c]);
      o.w = f2b(tile[r4 + 3][c]);
      *reinterpret_cast<ushort4*>(&d[(size_t)(c0 + c) * R + r0 + r4]) = o;
    }
  } else {
    int rb = bid - W1_BLOCKS;
    float* wg = smem_f;
    for (int i = tid * 4; i < NEXP * DIM; i += 256 * 4) {
      *reinterpret_cast<float4*>(wg + i) = *reinterpret_cast<const float4*>(Wg + i);
    }
    __syncthreads();
    int wave = tid >> 6, lane = tid & 63;
    int t = rb * 4 + wave;
    const float* xr = x + (size_t)t * DIM;
    unsigned short* xbr = xb + (size_t)t * DIM;
    float* outr = out + (size_t)t * DIM;
    double acc[NEXP];
#pragma unroll
    for (int e = 0; e < NEXP; e++) acc[e] = 0.0;
    for (int i = lane; i < DIM; i += 64) {
      float xf = xr[i];
      xbr[i] = f2b(xf);
      outr[i] = 0.0f;
      double xv = (double)xf;
#pragma unroll
      for (int e = 0; e < NEXP; e++) acc[e] += xv * (double)wg[e * DIM + i];
    }
#pragma unroll
    for (int e = 0; e < NEXP; e++) {
#pragma unroll
      for (int m = 1; m < 64; m <<= 1) acc[e] += __shfl_xor(acc[e], m, 64);
    }
    if (lane == 0) {
      int i0 = 0; double v0 = acc[0];
      for (int e = 1; e < NEXP; e++) { if (acc[e] > v0) { v0 = acc[e]; i0 = e; } }
      int i1 = -1; double v1 = -1e300;
      for (int e = 0; e < NEXP; e++) { if (e != i0 && acc[e] > v1) { v1 = acc[e]; i1 = e; } }
      double e1 = exp(v1 - v0);
      float g0 = (float)(1.0 / (1.0 + e1));
      float g1 = (float)(e1 / (1.0 + e1));
      top_i[t * 2] = i0; top_i[t * 2 + 1] = i1;
      gates[t * 2] = g0; gates[t * 2 + 1] = g1;
    }
  }
}

// ---------------- capacity scan (deterministic, token-major slot order) ----------------
__global__ __launch_bounds__(1024) void scan_kernel(const int* __restrict__ top_i,
                                                    const float* __restrict__ gates,
                                                    int* __restrict__ rowtok,
                                                    float* __restrict__ rowgate,
                                                    int* __restrict__ cnt) {
  __shared__ int hist[NEXP][1024];
  int t = threadIdx.x;
  int s0 = t * 8;
  int eloc[8];
  int c[NEXP];
#pragma unroll
  for (int e = 0; e < NEXP; e++) c[e] = 0;
#pragma unroll
  for (int j = 0; j < 8; j++) { int e = top_i[s0 + j]; eloc[j] = e; c[e]++; }
#pragma unroll
  for (int e = 0; e < NEXP; e++) hist[e][t] = c[e];
  __syncthreads();
  for (int step = 1; step < 1024; step <<= 1) {
    int tmp[NEXP];
#pragma unroll
    for (int e = 0; e < NEXP; e++) tmp[e] = (t >= step) ? hist[e][t - step] : 0;
    __syncthreads();
#pragma unroll
    for (int e = 0; e < NEXP; e++) hist[e][t] += tmp[e];
    __syncthreads();
  }
  int base[NEXP];
#pragma unroll
  for (int e = 0; e < NEXP; e++) base[e] = hist[e][t] - c[e];
  if (t < NEXP) {
    int tot = hist[t][1023];
    cnt[t] = tot < CAP ? tot : CAP;
  }
#pragma unroll
  for (int j = 0; j < 8; j++) {
    int s = s0 + j;
    int e = eloc[j];
    int pos = base[e]++;
    if (pos < CAP) {
      rowtok[e * CAP + pos] = s >> 1;
      rowgate[e * CAP + pos] = gates[s];
    }
  }
}

// ---------------- GEMM1 + GLU (z<8)  |  W2 transpose (z>=8) ----------------
// gemm1: 128m x 64n of H (both halves). trans planes: W2 [E][IDIM][DIM] f32 -> w2t [E][DIM][IDIM] bf16.
__global__ __launch_bounds__(256, 4) void gemm1_kernel(const unsigned short* __restrict__ xb,
                                                       const unsigned short* __restrict__ w1t,
                                                       const int* __restrict__ rowtok,
                                                       const int* __restrict__ cnt,
                                                       unsigned short* __restrict__ H,
                                                       const float* __restrict__ W2,
                                                       unsigned short* __restrict__ w2t) {
  __shared__ __align__(16) unsigned char smem[64 * 65 * 4];  // 16640 B, overlaid
  int tid  = threadIdx.x;
  int z = blockIdx.z;

  if (z >= NEXP) {
    // ---- W2 transpose plane ----
    int id = (z - NEXP) * (G1X * G1Y) + blockIdx.y * G1X + blockIdx.x;
    if (id >= W2_BLOCKS) return;
    float (*tile)[65] = reinterpret_cast<float (*)[65]>(smem);
    int e = id >> 9;
    int t = id & 511;
    const int R = IDIM, C = DIM;
    int r0 = (t & 31) * 64;
    int c0 = (t >> 5) * 64;
    const float* s = W2 + (size_t)e * R * C;
    unsigned short* d = w2t + (size_t)e * R * C;
    int tr = tid >> 4, tc = (tid & 15) * 4;
#pragma unroll
    for (int i = 0; i < 4; i++) {
      float4 v = *reinterpret_cast<const float4*>(&s[(size_t)(r0 + tr + i * 16) * C + c0 + tc]);
      tile[tr + i * 16][tc]     = v.x;
      tile[tr + i * 16][tc + 1] = v.y;
      tile[tr + i * 16][tc + 2] = v.z;
      tile[tr + i * 16][tc + 3] = v.w;
    }
    __syncthreads();
#pragma unroll
    for (int j = 0; j < 4; j++) {
      int c = (tid >> 4) + j * 16;
      int r4 = (tid & 15) * 4;
      ushort4 o;
      o.x = f2b(tile[r4][c]);
      o.y = f2b(tile[r4 + 1][c]);
      o.z = f2b(tile[r4 + 2][c]);
      o.w = f2b(tile[r4 + 3][c]);
      *reinterpret_cast<ushort4*>(&d[(size_t)(c0 + c) * R + r0 + r4]) = o;
    }
    return;
  }

  // ---- gemm1 path ----
  int e  = z;
  int m0 = blockIdx.y * 128;
  int i0 = blockIdx.x * 64;
  int cnte = cnt[e];
  if (m0 >= cnte) return;

  unsigned short* As = reinterpret_cast<unsigned short*>(smem);            // 128*32*2 = 8192 B
  unsigned short* Bi = reinterpret_cast<unsigned short*>(smem + 8192);     // 64*32*2  = 4096 B
  unsigned short* Bg = reinterpret_cast<unsigned short*>(smem + 12288);    // 64*32*2  = 4096 B

  int lane = tid & 63;
  int wave = tid >> 6;

  int srA0 = wave * 32 + (lane >> 2);
  int srA1 = srA0 + 16;
  int srB  = wave * 16 + (lane >> 2);
  int sk   = (lane & 3) * 8;

  int ma0 = m0 + srA0, ma1 = m0 + srA1;
  int tok0 = (ma0 < cnte) ? rowtok[e * CAP + ma0] : 0;
  int tok1 = (ma1 < cnte) ? rowtok[e * CAP + ma1] : 0;

  const unsigned short* w1e = w1t + (size_t)e * TWOI * DIM;
  const unsigned short* gA0 = xb + (size_t)tok0 * DIM + sk;
  const unsigned short* gA1 = xb + (size_t)tok1 * DIM + sk;
  const unsigned short* gBi = w1e + (size_t)(i0 + srB) * DIM + sk;
  const unsigned short* gBg = w1e + (size_t)(i0 + srB + IDIM) * DIM + sk;

  unsigned short* lA0 = As + (wave * 2 + 0) * 512;
  unsigned short* lA1 = As + (wave * 2 + 1) * 512;
  unsigned short* lBi = Bi + wave * 512;
  unsigned short* lBg = Bg + wave * 512;

  int lane16 = lane & 15;
  int quad   = lane >> 4;
  int wm = (wave & 1) * 64;
  int wn = (wave >> 1) * 32;

  floatx4 acc_i[4][2], acc_g[4][2];
#pragma unroll
  for (int i = 0; i < 4; i++)
#pragma unroll
    for (int j = 0; j < 2; j++) {
      acc_i[i][j] = (floatx4){0.f, 0.f, 0.f, 0.f};
      acc_g[i][j] = (floatx4){0.f, 0.f, 0.f, 0.f};
    }

  for (int k0 = 0; k0 < DIM; k0 += 32) {
    __syncthreads();
    async16(gA0 + k0, lA0);
    async16(gA1 + k0, lA1);
    async16(gBi + k0, lBi);
    async16(gBg + k0, lBg);
    __syncthreads();

    short8 a[4];
#pragma unroll
    for (int i = 0; i < 4; i++)
      a[i] = *(const short8*)&As[(wm + i * 16 + lane16) * 32 + quad * 8];
#pragma unroll
    for (int j = 0; j < 2; j++) {
      short8 bi = *(const short8*)&Bi[(wn + j * 16 + lane16) * 32 + quad * 8];
#pragma unroll
      for (int i = 0; i < 4; i++)
        acc_i[i][j] = __builtin_amdgcn_mfma_f32_16x16x32_bf16(a[i], bi, acc_i[i][j], 0, 0, 0);
      short8 bg = *(const short8*)&Bg[(wn + j * 16 + lane16) * 32 + quad * 8];
#pragma unroll
      for (int i = 0; i < 4; i++)
        acc_g[i][j] = __builtin_amdgcn_mfma_f32_16x16x32_bf16(a[i], bg, acc_g[i][j], 0, 0, 0);
    }
  }

  unsigned short* He = H + (size_t)e * CAP * IDIM;
#pragma unroll
  for (int i = 0; i < 4; i++) {
#pragma unroll
    for (int r = 0; r < 4; r++) {
      int m = m0 + wm + i * 16 + quad * 4 + r;
#pragma unroll
      for (int j = 0; j < 2; j++) {
        int n = i0 + wn + j * 16 + lane16;
        float vi = acc_i[i][j][r];
        float vg = acc_g[i][j][r];
        float h = 0.5f * vi * (1.0f + erff(vi * 0.70710678118654752f)) * vg;
        He[(size_t)m * IDIM + n] = f2b(h);
      }
    }
  }
}

// ---------------- GEMM2 + scatter-combine, K-split 2 ----------------
// z = expert + 8*khalf. 128m x 128n tile, K range [kh*1024, kh*1024+1024).
__global__ __launch_bounds__(256, 3) void gemm2_kernel(const unsigned short* __restrict__ H,
                                                       const unsigned short* __restrict__ w2t,
                                                       const int* __restrict__ cnt,
                                                       const int* __restrict__ rowtok,
                                                       const float* __restrict__ rowgate,
                                                       float* __restrict__ out) {
  int e  = blockIdx.z & 7;
  int kh = blockIdx.z >> 3;
  int m0 = blockIdx.y * 128;
  int n0 = blockIdx.x * 128;
  int cnte = cnt[e];
  if (m0 >= cnte) return;

  __shared__ __align__(16) unsigned short As[128 * 32];
  __shared__ __align__(16) unsigned short Bs[128 * 32];

  int tid  = threadIdx.x;
  int lane = tid & 63;
  int wave = tid >> 6;

  int sr0 = wave * 32 + (lane >> 2);
  int sr1 = sr0 + 16;
  int sk  = (lane & 3) * 8;
  int kbase = kh * (IDIM / 2);

  const unsigned short* He  = H + (size_t)e * CAP * IDIM;
  const unsigned short* w2e = w2t + (size_t)e * DIM * IDIM;
  const unsigned short* gA0 = He + (size_t)(m0 + sr0) * IDIM + kbase + sk;
  const unsigned short* gA1 = He + (size_t)(m0 + sr1) * IDIM + kbase + sk;
  const unsigned short* gB0 = w2e + (size_t)(n0 + sr0) * IDIM + kbase + sk;
  const unsigned short* gB1 = w2e + (size_t)(n0 + sr1) * IDIM + kbase + sk;

  unsigned short* lA0 = As + (wave * 2 + 0) * 512;
  unsigned short* lA1 = As + (wave * 2 + 1) * 512;
  unsigned short* lB0 = Bs + (wave * 2 + 0) * 512;
  unsigned short* lB1 = Bs + (wave * 2 + 1) * 512;

  int lane16 = lane & 15;
  int quad   = lane >> 4;
  int wm = (wave & 1) * 64;
  int wn = (wave >> 1) * 64;

  floatx4 acc[4][4];
#pragma unroll
  for (int i = 0; i < 4; i++)
#pragma unroll
    for (int j = 0; j < 4; j++) acc[i][j] = (floatx4){0.f, 0.f, 0.f, 0.f};

  for (int k0 = 0; k0 < IDIM / 2; k0 += 32) {
    __syncthreads();
    async16(gA0 + k0, lA0);
    async16(gA1 + k0, lA1);
    async16(gB0 + k0, lB0);
    async16(gB1 + k0, lB1);
    __syncthreads();

    short8 a[4];
#pragma unroll
    for (int i = 0; i < 4; i++)
      a[i] = *(const short8*)&As[(wm + i * 16 + lane16) * 32 + quad * 8];
#pragma unroll
    for (int j = 0; j < 4; j++) {
      short8 b = *(const short8*)&Bs[(wn + j * 16 + lane16) * 32 + quad * 8];
#pragma unroll
      for (int i = 0; i < 4; i++)
        acc[i][j] = __builtin_amdgcn_mfma_f32_16x16x32_bf16(a[i], b, acc[i][j], 0, 0, 0);
    }
  }

#pragma unroll
  for (int i = 0; i < 4; i++) {
#pragma unroll
    for (int r = 0; r < 4; r++) {
      int m = m0 + wm + i * 16 + quad * 4 + r;
      if (m < cnte) {
        int tok = rowtok[e * CAP + m];
        float g = rowgate[e * CAP + m];
        float* orow = out + (size_t)tok * DIM;
#pragma unroll
        for (int j = 0; j < 4; j++) {
          int n = n0 + wn + j * 16 + lane16;
          atomicAdd(orow + n, g * acc[i][j][r]);
        }
      }
    }
  }
}

// ---------------- launch ----------------
extern "C" void kernel_launch(void* const* d_in, const int* in_sizes, int n_in,
                              void* d_out, int out_size, void* d_ws, size_t ws_size,
                              hipStream_t stream) {
  const float* x  = (const float*)d_in[0];
  const float* Wg = (const float*)d_in[1];
  const float* W1 = (const float*)d_in[2];
  const float* W2 = (const float*)d_in[3];
  float* out = (float*)d_out;

  char* ws = (char*)d_ws;
  size_t off = 0;
  auto alloc = [&](size_t bytes) -> void* {
    void* p = ws + off;
    off = (off + bytes + 255) & ~(size_t)255;
    return p;
  };
  int*   top_i   = (int*)alloc((size_t)N_TOK * 2 * sizeof(int));
  float* gates   = (float*)alloc((size_t)N_TOK * 2 * sizeof(float));
  int*   rowtok  = (int*)alloc((size_t)NEXP * CAP * sizeof(int));
  float* rowgate = (float*)alloc((size_t)NEXP * CAP * sizeof(float));
  int*   cnt     = (int*)alloc((size_t)NEXP * sizeof(int));
  unsigned short* xb  = (unsigned short*)alloc((size_t)N_TOK * DIM * 2);
  unsigned short* w1t = (unsigned short*)alloc((size_t)NEXP * TWOI * DIM * 2);
  unsigned short* w2t = (unsigned short*)alloc((size_t)NEXP * DIM * IDIM * 2);
  unsigned short* Hb  = (unsigned short*)alloc((size_t)NEXP * CAP * IDIM * 2);
  if (off > ws_size) return;

  hipLaunchKernelGGL(prologue_kernel, dim3(W1_BLOCKS + ROUTER_BLOCKS), dim3(256), 0, stream,
                     W1, w1t, x, Wg, xb, out, top_i, gates);
  hipLaunchKernelGGL(scan_kernel, dim3(1), dim3(1024), 0, stream,
                     top_i, gates, rowtok, rowgate, cnt);
  hipLaunchKernelGGL(gemm1_kernel, dim3(G1X, G1Y, NEXP + G1_TRANS_Z), dim3(256), 0, stream,
                     xb, w1t, rowtok, cnt, Hb, W2, w2t);
  hipLaunchKernelGGL(gemm2_kernel, dim3(DIM / 128, CAP / 128, 16), dim3(256), 0, stream,
                     Hb, w2t, cnt, rowtok, rowgate, out);
}

// Round 6
// 459.078 us; speedup vs baseline: 1.0446x; 1.0271x over previous
//
#include <hip/hip_runtime.h>
#include <hip/hip_bf16.h>
#include <math.h>

#define N_TOK 4096
#define DIM   1024
#define NEXP  8
#define IDIM  2048
#define TWOI  4096
#define CAP   1280

#define W1_BLOCKS (64 * 16 * NEXP)   // 8192 transpose tiles for W1
#define W2_BLOCKS (16 * 32 * NEXP)   // 4096 transpose tiles for W2
#define ROUTER_BLOCKS (N_TOK / 4)    // 1024

// gemm1 grid: x=32 n-tiles, y=10 m-tiles, z = 8 experts + 13 trans planes (320 blocks each)
#define G1X 32
#define G1Y 10
#define G1_TRANS_Z ((W2_BLOCKS + G1X * G1Y - 1) / (G1X * G1Y))  // 13

using short8  = __attribute__((ext_vector_type(8))) short;
using floatx4 = __attribute__((ext_vector_type(4))) float;

__device__ __forceinline__ unsigned short f2b(float f) {
  __hip_bfloat16 h = __float2bfloat16(f);
  return *reinterpret_cast<unsigned short*>(&h);
}

// async global->LDS, 16B per lane. LDS dst = wave-uniform base + lane*16.
__device__ __forceinline__ void async16(const unsigned short* g, unsigned short* l) {
  __builtin_amdgcn_global_load_lds(
      (const __attribute__((address_space(1))) unsigned int*)g,
      (__attribute__((address_space(3))) unsigned int*)l,
      16, 0, 0);
}

// ---------------- prologue: W1 transpose+convert AND router ----------------
__global__ __launch_bounds__(256) void prologue_kernel(const float* __restrict__ W1,
                                                       unsigned short* __restrict__ w1t,
                                                       const float* __restrict__ x,
                                                       const float* __restrict__ Wg,
                                                       unsigned short* __restrict__ xb,
                                                       int* __restrict__ top_i,
                                                       float* __restrict__ gates) {
  __shared__ __align__(16) float smem_f[NEXP * DIM];   // 32 KB, overlaid
  int bid = blockIdx.x;
  int tid = threadIdx.x;

  if (bid < W1_BLOCKS) {
    float (*tile)[65] = reinterpret_cast<float (*)[65]>(smem_f);
    int e = bid >> 10;
    int t = bid & 1023;
    const int R = DIM, C = TWOI;
    int r0 = (t & 15) * 64;
    int c0 = (t >> 4) * 64;
    const float* s = W1 + (size_t)e * R * C;
    unsigned short* d = w1t + (size_t)e * R * C;
    int tr = tid >> 4, tc = (tid & 15) * 4;
#pragma unroll
    for (int i = 0; i < 4; i++) {
      float4 v = *reinterpret_cast<const float4*>(&s[(size_t)(r0 + tr + i * 16) * C + c0 + tc]);
      tile[tr + i * 16][tc]     = v.x;
      tile[tr + i * 16][tc + 1] = v.y;
      tile[tr + i * 16][tc + 2] = v.z;
      tile[tr + i * 16][tc + 3] = v.w;
    }
    __syncthreads();
#pragma unroll
    for (int j = 0; j < 4; j++) {
      int c = (tid >> 4) + j * 16;
      int r4 = (tid & 15) * 4;
      ushort4 o;
      o.x = f2b(tile[r4][c]);
      o.y = f2b(tile[r4 + 1][c]);
      o.z = f2b(tile[r4 + 2][c]);
      o.w = f2b(tile[r4 + 3][c]);
      *reinterpret_cast<ushort4*>(&d[(size_t)(c0 + c) * R + r0 + r4]) = o;
    }
  } else {
    int rb = bid - W1_BLOCKS;
    float* wg = smem_f;
    for (int i = tid * 4; i < NEXP * DIM; i += 256 * 4) {
      *reinterpret_cast<float4*>(wg + i) = *reinterpret_cast<const float4*>(Wg + i);
    }
    __syncthreads();
    int wave = tid >> 6, lane = tid & 63;
    int t = rb * 4 + wave;
    const float* xr = x + (size_t)t * DIM;
    unsigned short* xbr = xb + (size_t)t * DIM;
    double acc[NEXP];
#pragma unroll
    for (int e = 0; e < NEXP; e++) acc[e] = 0.0;
    for (int i = lane; i < DIM; i += 64) {
      float xf = xr[i];
      xbr[i] = f2b(xf);
      double xv = (double)xf;
#pragma unroll
      for (int e = 0; e < NEXP; e++) acc[e] += xv * (double)wg[e * DIM + i];
    }
#pragma unroll
    for (int e = 0; e < NEXP; e++) {
#pragma unroll
      for (int m = 1; m < 64; m <<= 1) acc[e] += __shfl_xor(acc[e], m, 64);
    }
    if (lane == 0) {
      int i0 = 0; double v0 = acc[0];
      for (int e = 1; e < NEXP; e++) { if (acc[e] > v0) { v0 = acc[e]; i0 = e; } }
      int i1 = -1; double v1 = -1e300;
      for (int e = 0; e < NEXP; e++) { if (e != i0 && acc[e] > v1) { v1 = acc[e]; i1 = e; } }
      double e1 = exp(v1 - v0);
      float g0 = (float)(1.0 / (1.0 + e1));
      float g1 = (float)(e1 / (1.0 + e1));
      top_i[t * 2] = i0; top_i[t * 2 + 1] = i1;
      gates[t * 2] = g0; gates[t * 2 + 1] = g1;
    }
  }
}

// ---------------- capacity scan (deterministic, token-major slot order) ----------------
__global__ __launch_bounds__(1024) void scan_kernel(const int* __restrict__ top_i,
                                                    const float* __restrict__ gates,
                                                    int* __restrict__ rowtok,
                                                    int* __restrict__ slotpos,
                                                    float* __restrict__ tokgate,
                                                    int* __restrict__ cnt) {
  __shared__ int hist[NEXP][1024];
  int t = threadIdx.x;
  int s0 = t * 8;
  int eloc[8];
  int c[NEXP];
#pragma unroll
  for (int e = 0; e < NEXP; e++) c[e] = 0;
#pragma unroll
  for (int j = 0; j < 8; j++) { int e = top_i[s0 + j]; eloc[j] = e; c[e]++; }
#pragma unroll
  for (int e = 0; e < NEXP; e++) hist[e][t] = c[e];
  __syncthreads();
  for (int step = 1; step < 1024; step <<= 1) {
    int tmp[NEXP];
#pragma unroll
    for (int e = 0; e < NEXP; e++) tmp[e] = (t >= step) ? hist[e][t - step] : 0;
    __syncthreads();
#pragma unroll
    for (int e = 0; e < NEXP; e++) hist[e][t] += tmp[e];
    __syncthreads();
  }
  int base[NEXP];
#pragma unroll
  for (int e = 0; e < NEXP; e++) base[e] = hist[e][t] - c[e];
  if (t < NEXP) {
    int tot = hist[t][1023];
    cnt[t] = tot < CAP ? tot : CAP;
  }
#pragma unroll
  for (int j = 0; j < 8; j++) {
    int s = s0 + j;
    int e = eloc[j];
    int pos = base[e]++;
    bool keep = pos < CAP;
    slotpos[s] = keep ? pos : 0;
    tokgate[s] = keep ? gates[s] : 0.0f;
    if (keep) rowtok[e * CAP + pos] = s >> 1;
  }
}

// ---------------- GEMM1 + GLU (z<8)  |  W2 transpose (z>=8) ----------------
__global__ __launch_bounds__(256, 4) void gemm1_kernel(const unsigned short* __restrict__ xb,
                                                       const unsigned short* __restrict__ w1t,
                                                       const int* __restrict__ rowtok,
                                                       const int* __restrict__ cnt,
                                                       unsigned short* __restrict__ H,
                                                       const float* __restrict__ W2,
                                                       unsigned short* __restrict__ w2t) {
  __shared__ __align__(16) unsigned char smem[64 * 65 * 4];  // 16640 B, overlaid
  int tid  = threadIdx.x;
  int z = blockIdx.z;

  if (z >= NEXP) {
    // ---- W2 transpose plane ----
    int id = (z - NEXP) * (G1X * G1Y) + blockIdx.y * G1X + blockIdx.x;
    if (id >= W2_BLOCKS) return;
    float (*tile)[65] = reinterpret_cast<float (*)[65]>(smem);
    int e = id >> 9;
    int t = id & 511;
    const int R = IDIM, C = DIM;
    int r0 = (t & 31) * 64;
    int c0 = (t >> 5) * 64;
    const float* s = W2 + (size_t)e * R * C;
    unsigned short* d = w2t + (size_t)e * R * C;
    int tr = tid >> 4, tc = (tid & 15) * 4;
#pragma unroll
    for (int i = 0; i < 4; i++) {
      float4 v = *reinterpret_cast<const float4*>(&s[(size_t)(r0 + tr + i * 16) * C + c0 + tc]);
      tile[tr + i * 16][tc]     = v.x;
      tile[tr + i * 16][tc + 1] = v.y;
      tile[tr + i * 16][tc + 2] = v.z;
      tile[tr + i * 16][tc + 3] = v.w;
    }
    __syncthreads();
#pragma unroll
    for (int j = 0; j < 4; j++) {
      int c = (tid >> 4) + j * 16;
      int r4 = (tid & 15) * 4;
      ushort4 o;
      o.x = f2b(tile[r4][c]);
      o.y = f2b(tile[r4 + 1][c]);
      o.z = f2b(tile[r4 + 2][c]);
      o.w = f2b(tile[r4 + 3][c]);
      *reinterpret_cast<ushort4*>(&d[(size_t)(c0 + c) * R + r0 + r4]) = o;
    }
    return;
  }

  // ---- gemm1 path ----
  int e  = z;
  int m0 = blockIdx.y * 128;
  int i0 = blockIdx.x * 64;
  int cnte = cnt[e];
  if (m0 >= cnte) return;

  unsigned short* As = reinterpret_cast<unsigned short*>(smem);            // 8192 B
  unsigned short* Bi = reinterpret_cast<unsigned short*>(smem + 8192);     // 4096 B
  unsigned short* Bg = reinterpret_cast<unsigned short*>(smem + 12288);    // 4096 B

  int lane = tid & 63;
  int wave = tid >> 6;

  int srA0 = wave * 32 + (lane >> 2);
  int srA1 = srA0 + 16;
  int srB  = wave * 16 + (lane >> 2);
  int sk   = (lane & 3) * 8;

  int ma0 = m0 + srA0, ma1 = m0 + srA1;
  int tok0 = (ma0 < cnte) ? rowtok[e * CAP + ma0] : 0;
  int tok1 = (ma1 < cnte) ? rowtok[e * CAP + ma1] : 0;

  const unsigned short* w1e = w1t + (size_t)e * TWOI * DIM;
  const unsigned short* gA0 = xb + (size_t)tok0 * DIM + sk;
  const unsigned short* gA1 = xb + (size_t)tok1 * DIM + sk;
  const unsigned short* gBi = w1e + (size_t)(i0 + srB) * DIM + sk;
  const unsigned short* gBg = w1e + (size_t)(i0 + srB + IDIM) * DIM + sk;

  unsigned short* lA0 = As + (wave * 2 + 0) * 512;
  unsigned short* lA1 = As + (wave * 2 + 1) * 512;
  unsigned short* lBi = Bi + wave * 512;
  unsigned short* lBg = Bg + wave * 512;

  int lane16 = lane & 15;
  int quad   = lane >> 4;
  int wm = (wave & 1) * 64;
  int wn = (wave >> 1) * 32;

  floatx4 acc_i[4][2], acc_g[4][2];
#pragma unroll
  for (int i = 0; i < 4; i++)
#pragma unroll
    for (int j = 0; j < 2; j++) {
      acc_i[i][j] = (floatx4){0.f, 0.f, 0.f, 0.f};
      acc_g[i][j] = (floatx4){0.f, 0.f, 0.f, 0.f};
    }

  for (int k0 = 0; k0 < DIM; k0 += 32) {
    __syncthreads();
    async16(gA0 + k0, lA0);
    async16(gA1 + k0, lA1);
    async16(gBi + k0, lBi);
    async16(gBg + k0, lBg);
    __syncthreads();

    short8 a[4];
#pragma unroll
    for (int i = 0; i < 4; i++)
      a[i] = *(const short8*)&As[(wm + i * 16 + lane16) * 32 + quad * 8];
#pragma unroll
    for (int j = 0; j < 2; j++) {
      short8 bi = *(const short8*)&Bi[(wn + j * 16 + lane16) * 32 + quad * 8];
#pragma unroll
      for (int i = 0; i < 4; i++)
        acc_i[i][j] = __builtin_amdgcn_mfma_f32_16x16x32_bf16(a[i], bi, acc_i[i][j], 0, 0, 0);
      short8 bg = *(const short8*)&Bg[(wn + j * 16 + lane16) * 32 + quad * 8];
#pragma unroll
      for (int i = 0; i < 4; i++)
        acc_g[i][j] = __builtin_amdgcn_mfma_f32_16x16x32_bf16(a[i], bg, acc_g[i][j], 0, 0, 0);
    }
  }

  unsigned short* He = H + (size_t)e * CAP * IDIM;
#pragma unroll
  for (int i = 0; i < 4; i++) {
#pragma unroll
    for (int r = 0; r < 4; r++) {
      int m = m0 + wm + i * 16 + quad * 4 + r;
#pragma unroll
      for (int j = 0; j < 2; j++) {
        int n = i0 + wn + j * 16 + lane16;
        float vi = acc_i[i][j][r];
        float vg = acc_g[i][j][r];
        float h = 0.5f * vi * (1.0f + erff(vi * 0.70710678118654752f)) * vg;
        He[(size_t)m * IDIM + n] = f2b(h);
      }
    }
  }
}

// ---------------- GEMM2, K-split 2, plain stores to partial buffers ----------------
// z = expert + 8*kh. 128m x 128n tile, K range [kh*1024, +1024). No atomics.
__global__ __launch_bounds__(256, 4) void gemm2_kernel(const unsigned short* __restrict__ H,
                                                       const unsigned short* __restrict__ w2t,
                                                       const int* __restrict__ cnt,
                                                       float* __restrict__ expoutP) {
  int e  = blockIdx.z & 7;
  int kh = blockIdx.z >> 3;
  int m0 = blockIdx.y * 128;
  int n0 = blockIdx.x * 128;
  int cnte = cnt[e];
  if (m0 >= cnte) return;

  __shared__ __align__(16) unsigned short As[128 * 32];
  __shared__ __align__(16) unsigned short Bs[128 * 32];

  int tid  = threadIdx.x;
  int lane = tid & 63;
  int wave = tid >> 6;

  int sr0 = wave * 32 + (lane >> 2);
  int sr1 = sr0 + 16;
  int sk  = (lane & 3) * 8;
  int kbase = kh * (IDIM / 2);

  const unsigned short* He  = H + (size_t)e * CAP * IDIM;
  const unsigned short* w2e = w2t + (size_t)e * DIM * IDIM;
  const unsigned short* gA0 = He + (size_t)(m0 + sr0) * IDIM + kbase + sk;
  const unsigned short* gA1 = He + (size_t)(m0 + sr1) * IDIM + kbase + sk;
  const unsigned short* gB0 = w2e + (size_t)(n0 + sr0) * IDIM + kbase + sk;
  const unsigned short* gB1 = w2e + (size_t)(n0 + sr1) * IDIM + kbase + sk;

  unsigned short* lA0 = As + (wave * 2 + 0) * 512;
  unsigned short* lA1 = As + (wave * 2 + 1) * 512;
  unsigned short* lB0 = Bs + (wave * 2 + 0) * 512;
  unsigned short* lB1 = Bs + (wave * 2 + 1) * 512;

  int lane16 = lane & 15;
  int quad   = lane >> 4;
  int wm = (wave & 1) * 64;
  int wn = (wave >> 1) * 64;

  floatx4 acc[4][4];
#pragma unroll
  for (int i = 0; i < 4; i++)
#pragma unroll
    for (int j = 0; j < 4; j++) acc[i][j] = (floatx4){0.f, 0.f, 0.f, 0.f};

  for (int k0 = 0; k0 < IDIM / 2; k0 += 32) {
    __syncthreads();
    async16(gA0 + k0, lA0);
    async16(gA1 + k0, lA1);
    async16(gB0 + k0, lB0);
    async16(gB1 + k0, lB1);
    __syncthreads();

    short8 a[4];
#pragma unroll
    for (int i = 0; i < 4; i++)
      a[i] = *(const short8*)&As[(wm + i * 16 + lane16) * 32 + quad * 8];
#pragma unroll
    for (int j = 0; j < 4; j++) {
      short8 b = *(const short8*)&Bs[(wn + j * 16 + lane16) * 32 + quad * 8];
#pragma unroll
      for (int i = 0; i < 4; i++)
        acc[i][j] = __builtin_amdgcn_mfma_f32_16x16x32_bf16(a[i], b, acc[i][j], 0, 0, 0);
    }
  }

  float* oute = expoutP + ((size_t)kh * NEXP + e) * CAP * DIM;
#pragma unroll
  for (int i = 0; i < 4; i++) {
#pragma unroll
    for (int r = 0; r < 4; r++) {
      int m = m0 + wm + i * 16 + quad * 4 + r;
#pragma unroll
      for (int j = 0; j < 4; j++) {
        int n = n0 + wn + j * 16 + lane16;
        oute[(size_t)m * DIM + n] = acc[i][j][r];
      }
    }
  }
}

// ---------------- combine: out[tok] = g0*(P0+P1)[e0,p0] + g1*(P0+P1)[e1,p1] ----------------
__global__ __launch_bounds__(256) void combine_kernel(const int* __restrict__ top_i,
                                                      const int* __restrict__ slotpos,
                                                      const float* __restrict__ tokgate,
                                                      const float* __restrict__ expoutP,
                                                      float* __restrict__ out) {
  int t = blockIdx.x;
  int tid = threadIdx.x;
  int e0 = top_i[t * 2], e1 = top_i[t * 2 + 1];
  int p0 = slotpos[t * 2], p1 = slotpos[t * 2 + 1];
  float g0 = tokgate[t * 2], g1 = tokgate[t * 2 + 1];
  const float4* a0 = reinterpret_cast<const float4*>(expoutP + ((size_t)e0 * CAP + p0) * DIM);
  const float4* a1 = reinterpret_cast<const float4*>(expoutP + ((size_t)(NEXP + e0) * CAP + p0) * DIM);
  const float4* b0 = reinterpret_cast<const float4*>(expoutP + ((size_t)e1 * CAP + p1) * DIM);
  const float4* b1 = reinterpret_cast<const float4*>(expoutP + ((size_t)(NEXP + e1) * CAP + p1) * DIM);
  float4 va0 = a0[tid], va1 = a1[tid], vb0 = b0[tid], vb1 = b1[tid];
  float4 o;
  o.x = g0 * (va0.x + va1.x) + g1 * (vb0.x + vb1.x);
  o.y = g0 * (va0.y + va1.y) + g1 * (vb0.y + vb1.y);
  o.z = g0 * (va0.z + va1.z) + g1 * (vb0.z + vb1.z);
  o.w = g0 * (va0.w + va1.w) + g1 * (vb0.w + vb1.w);
  reinterpret_cast<float4*>(out + (size_t)t * DIM)[tid] = o;
}

// ---------------- launch ----------------
extern "C" void kernel_launch(void* const* d_in, const int* in_sizes, int n_in,
                              void* d_out, int out_size, void* d_ws, size_t ws_size,
                              hipStream_t stream) {
  const float* x  = (const float*)d_in[0];
  const float* Wg = (const float*)d_in[1];
  const float* W1 = (const float*)d_in[2];
  const float* W2 = (const float*)d_in[3];
  float* out = (float*)d_out;

  char* ws = (char*)d_ws;
  size_t off = 0;
  auto alloc = [&](size_t bytes) -> void* {
    void* p = ws + off;
    off = (off + bytes + 255) & ~(size_t)255;
    return p;
  };
  int*   top_i   = (int*)alloc((size_t)N_TOK * 2 * sizeof(int));
  float* gates   = (float*)alloc((size_t)N_TOK * 2 * sizeof(float));
  int*   rowtok  = (int*)alloc((size_t)NEXP * CAP * sizeof(int));
  int*   slotpos = (int*)alloc((size_t)N_TOK * 2 * sizeof(int));
  float* tokgate = (float*)alloc((size_t)N_TOK * 2 * sizeof(float));
  int*   cnt     = (int*)alloc((size_t)NEXP * sizeof(int));
  unsigned short* xb  = (unsigned short*)alloc((size_t)N_TOK * DIM * 2);
  unsigned short* w1t = (unsigned short*)alloc((size_t)NEXP * TWOI * DIM * 2);
  unsigned short* w2t = (unsigned short*)alloc((size_t)NEXP * DIM * IDIM * 2);
  unsigned short* Hb  = (unsigned short*)alloc((size_t)NEXP * CAP * IDIM * 2);
  float* expoutP = (float*)alloc((size_t)2 * NEXP * CAP * DIM * sizeof(float));
  if (off > ws_size) return;

  hipLaunchKernelGGL(prologue_kernel, dim3(W1_BLOCKS + ROUTER_BLOCKS), dim3(256), 0, stream,
                     W1, w1t, x, Wg, xb, top_i, gates);
  hipLaunchKernelGGL(scan_kernel, dim3(1), dim3(1024), 0, stream,
                     top_i, gates, rowtok, slotpos, tokgate, cnt);
  hipLaunchKernelGGL(gemm1_kernel, dim3(G1X, G1Y, NEXP + G1_TRANS_Z), dim3(256), 0, stream,
                     xb, w1t, rowtok, cnt, Hb, W2, w2t);
  hipLaunchKernelGGL(gemm2_kernel, dim3(DIM / 128, CAP / 128, 16), dim3(256), 0, stream,
                     Hb, w2t, cnt, expoutP);
  hipLaunchKernelGGL(combine_kernel, dim3(N_TOK), dim3(256), 0, stream,
                     top_i, slotpos, tokgate, expoutP, out);
}

// Round 7
// 439.357 us; speedup vs baseline: 1.0915x; 1.0449x over previous
//
#include <hip/hip_runtime.h>
#include <hip/hip_bf16.h>
#include <math.h>

#define N_TOK 4096
#define DIM   1024
#define NEXP  8
#define IDIM  2048
#define TWOI  4096
#define CAP   1280

#define W1_BLOCKS (64 * 16 * NEXP)   // 8192 transpose tiles for W1
#define W2_BLOCKS (16 * 32 * NEXP)   // 4096 transpose tiles for W2
#define ROUTER_BLOCKS (N_TOK / 4)    // 1024

// gemm1 grid: x=32 n-tiles, y=10 m-tiles, z = 8 experts + 13 trans planes (320 blocks each)
#define G1X 32
#define G1Y 10
#define G1_TRANS_Z ((W2_BLOCKS + G1X * G1Y - 1) / (G1X * G1Y))  // 13

using short8  = __attribute__((ext_vector_type(8))) short;
using floatx4 = __attribute__((ext_vector_type(4))) float;

__device__ __forceinline__ unsigned short f2b(float f) {
  __hip_bfloat16 h = __float2bfloat16(f);
  return *reinterpret_cast<unsigned short*>(&h);
}

// async global->LDS, 16B per lane. LDS dst = wave-uniform base + lane*16.
__device__ __forceinline__ void async16(const unsigned short* g, unsigned short* l) {
  __builtin_amdgcn_global_load_lds(
      (const __attribute__((address_space(1))) unsigned int*)g,
      (__attribute__((address_space(3))) unsigned int*)l,
      16, 0, 0);
}

// ---------------- prologue: W1 transpose+convert AND router ----------------
__global__ __launch_bounds__(256) void prologue_kernel(const float* __restrict__ W1,
                                                       unsigned short* __restrict__ w1t,
                                                       const float* __restrict__ x,
                                                       const float* __restrict__ Wg,
                                                       unsigned short* __restrict__ xb,
                                                       int* __restrict__ top_i,
                                                       float* __restrict__ gates) {
  __shared__ __align__(16) float smem_f[NEXP * DIM];   // 32 KB, overlaid
  int bid = blockIdx.x;
  int tid = threadIdx.x;

  if (bid < W1_BLOCKS) {
    float (*tile)[65] = reinterpret_cast<float (*)[65]>(smem_f);
    int e = bid >> 10;
    int t = bid & 1023;
    const int R = DIM, C = TWOI;
    int r0 = (t & 15) * 64;
    int c0 = (t >> 4) * 64;
    const float* s = W1 + (size_t)e * R * C;
    unsigned short* d = w1t + (size_t)e * R * C;
    int tr = tid >> 4, tc = (tid & 15) * 4;
#pragma unroll
    for (int i = 0; i < 4; i++) {
      float4 v = *reinterpret_cast<const float4*>(&s[(size_t)(r0 + tr + i * 16) * C + c0 + tc]);
      tile[tr + i * 16][tc]     = v.x;
      tile[tr + i * 16][tc + 1] = v.y;
      tile[tr + i * 16][tc + 2] = v.z;
      tile[tr + i * 16][tc + 3] = v.w;
    }
    __syncthreads();
#pragma unroll
    for (int j = 0; j < 4; j++) {
      int c = (tid >> 4) + j * 16;
      int r4 = (tid & 15) * 4;
      ushort4 o;
      o.x = f2b(tile[r4][c]);
      o.y = f2b(tile[r4 + 1][c]);
      o.z = f2b(tile[r4 + 2][c]);
      o.w = f2b(tile[r4 + 3][c]);
      *reinterpret_cast<ushort4*>(&d[(size_t)(c0 + c) * R + r0 + r4]) = o;
    }
  } else {
    int rb = bid - W1_BLOCKS;
    float* wg = smem_f;
    for (int i = tid * 4; i < NEXP * DIM; i += 256 * 4) {
      *reinterpret_cast<float4*>(wg + i) = *reinterpret_cast<const float4*>(Wg + i);
    }
    __syncthreads();
    int wave = tid >> 6, lane = tid & 63;
    int t = rb * 4 + wave;
    const float* xr = x + (size_t)t * DIM;
    unsigned short* xbr = xb + (size_t)t * DIM;
    double acc[NEXP];
#pragma unroll
    for (int e = 0; e < NEXP; e++) acc[e] = 0.0;
    for (int i = lane; i < DIM; i += 64) {
      float xf = xr[i];
      xbr[i] = f2b(xf);
      double xv = (double)xf;
#pragma unroll
      for (int e = 0; e < NEXP; e++) acc[e] += xv * (double)wg[e * DIM + i];
    }
#pragma unroll
    for (int e = 0; e < NEXP; e++) {
#pragma unroll
      for (int m = 1; m < 64; m <<= 1) acc[e] += __shfl_xor(acc[e], m, 64);
    }
    if (lane == 0) {
      int i0 = 0; double v0 = acc[0];
      for (int e = 1; e < NEXP; e++) { if (acc[e] > v0) { v0 = acc[e]; i0 = e; } }
      int i1 = -1; double v1 = -1e300;
      for (int e = 0; e < NEXP; e++) { if (e != i0 && acc[e] > v1) { v1 = acc[e]; i1 = e; } }
      double e1 = exp(v1 - v0);
      float g0 = (float)(1.0 / (1.0 + e1));
      float g1 = (float)(e1 / (1.0 + e1));
      top_i[t * 2] = i0; top_i[t * 2 + 1] = i1;
      gates[t * 2] = g0; gates[t * 2 + 1] = g1;
    }
  }
}

// ---------------- capacity scan (deterministic, token-major slot order) ----------------
__global__ __launch_bounds__(1024) void scan_kernel(const int* __restrict__ top_i,
                                                    const float* __restrict__ gates,
                                                    int* __restrict__ rowtok,
                                                    int* __restrict__ rowslot,
                                                    float* __restrict__ rowgate,
                                                    float* __restrict__ tokgate,
                                                    int* __restrict__ cnt) {
  __shared__ int hist[NEXP][1024];
  int t = threadIdx.x;
  int s0 = t * 8;
  int eloc[8];
  int c[NEXP];
#pragma unroll
  for (int e = 0; e < NEXP; e++) c[e] = 0;
#pragma unroll
  for (int j = 0; j < 8; j++) { int e = top_i[s0 + j]; eloc[j] = e; c[e]++; }
#pragma unroll
  for (int e = 0; e < NEXP; e++) hist[e][t] = c[e];
  __syncthreads();
  for (int step = 1; step < 1024; step <<= 1) {
    int tmp[NEXP];
#pragma unroll
    for (int e = 0; e < NEXP; e++) tmp[e] = (t >= step) ? hist[e][t - step] : 0;
    __syncthreads();
#pragma unroll
    for (int e = 0; e < NEXP; e++) hist[e][t] += tmp[e];
    __syncthreads();
  }
  int base[NEXP];
#pragma unroll
  for (int e = 0; e < NEXP; e++) base[e] = hist[e][t] - c[e];
  if (t < NEXP) {
    int tot = hist[t][1023];
    cnt[t] = tot < CAP ? tot : CAP;
  }
#pragma unroll
  for (int j = 0; j < 8; j++) {
    int s = s0 + j;
    int e = eloc[j];
    int pos = base[e]++;
    bool keep = pos < CAP;
    tokgate[s] = keep ? gates[s] : 0.0f;   // 0 marks a dropped slot (real gates are > 0)
    if (keep) {
      rowtok[e * CAP + pos]  = s >> 1;
      rowslot[e * CAP + pos] = s & 1;
      rowgate[e * CAP + pos] = gates[s];
    }
  }
}

// ---------------- GEMM1 + GLU (z<8)  |  W2 transpose (z>=8) ----------------
// BK=64 via dual 32-wide LDS buffers (half the barriers, keeps 64B-row bank-free layout).
__global__ __launch_bounds__(256, 4) void gemm1_kernel(const unsigned short* __restrict__ xb,
                                                       const unsigned short* __restrict__ w1t,
                                                       const int* __restrict__ rowtok,
                                                       const int* __restrict__ cnt,
                                                       unsigned short* __restrict__ H,
                                                       const float* __restrict__ W2,
                                                       unsigned short* __restrict__ w2t) {
  __shared__ __align__(16) unsigned char smem[32768];  // gemm: 32 KB; trans overlay: 16.6 KB
  int tid  = threadIdx.x;
  int z = blockIdx.z;

  if (z >= NEXP) {
    // ---- W2 transpose plane ----
    int id = (z - NEXP) * (G1X * G1Y) + blockIdx.y * G1X + blockIdx.x;
    if (id >= W2_BLOCKS) return;
    float (*tile)[65] = reinterpret_cast<float (*)[65]>(smem);
    int e = id >> 9;
    int t = id & 511;
    const int R = IDIM, C = DIM;
    int r0 = (t & 31) * 64;
    int c0 = (t >> 5) * 64;
    const float* s = W2 + (size_t)e * R * C;
    unsigned short* d = w2t + (size_t)e * R * C;
    int tr = tid >> 4, tc = (tid & 15) * 4;
#pragma unroll
    for (int i = 0; i < 4; i++) {
      float4 v = *reinterpret_cast<const float4*>(&s[(size_t)(r0 + tr + i * 16) * C + c0 + tc]);
      tile[tr + i * 16][tc]     = v.x;
      tile[tr + i * 16][tc + 1] = v.y;
      tile[tr + i * 16][tc + 2] = v.z;
      tile[tr + i * 16][tc + 3] = v.w;
    }
    __syncthreads();
#pragma unroll
    for (int j = 0; j < 4; j++) {
      int c = (tid >> 4) + j * 16;
      int r4 = (tid & 15) * 4;
      ushort4 o;
      o.x = f2b(tile[r4][c]);
      o.y = f2b(tile[r4 + 1][c]);
      o.z = f2b(tile[r4 + 2][c]);
      o.w = f2b(tile[r4 + 3][c]);
      *reinterpret_cast<ushort4*>(&d[(size_t)(c0 + c) * R + r0 + r4]) = o;
    }
    return;
  }

  // ---- gemm1 path ----
  int e  = z;
  int m0 = blockIdx.y * 128;
  int i0 = blockIdx.x * 64;
  int cnte = cnt[e];
  if (m0 >= cnte) return;

  unsigned short* As[2] = { (unsigned short*)smem,           (unsigned short*)(smem + 8192) };
  unsigned short* Bi[2] = { (unsigned short*)(smem + 16384), (unsigned short*)(smem + 20480) };
  unsigned short* Bg[2] = { (unsigned short*)(smem + 24576), (unsigned short*)(smem + 28672) };

  int lane = tid & 63;
  int wave = tid >> 6;

  int srA0 = wave * 32 + (lane >> 2);
  int srA1 = srA0 + 16;
  int srB  = wave * 16 + (lane >> 2);
  int sk   = (lane & 3) * 8;

  int ma0 = m0 + srA0, ma1 = m0 + srA1;
  int tok0 = (ma0 < cnte) ? rowtok[e * CAP + ma0] : 0;
  int tok1 = (ma1 < cnte) ? rowtok[e * CAP + ma1] : 0;

  const unsigned short* w1e = w1t + (size_t)e * TWOI * DIM;
  const unsigned short* gA0 = xb + (size_t)tok0 * DIM + sk;
  const unsigned short* gA1 = xb + (size_t)tok1 * DIM + sk;
  const unsigned short* gBi = w1e + (size_t)(i0 + srB) * DIM + sk;
  const unsigned short* gBg = w1e + (size_t)(i0 + srB + IDIM) * DIM + sk;

  int lane16 = lane & 15;
  int quad   = lane >> 4;
  int wm = (wave & 1) * 64;
  int wn = (wave >> 1) * 32;

  floatx4 acc_i[4][2], acc_g[4][2];
#pragma unroll
  for (int i = 0; i < 4; i++)
#pragma unroll
    for (int j = 0; j < 2; j++) {
      acc_i[i][j] = (floatx4){0.f, 0.f, 0.f, 0.f};
      acc_g[i][j] = (floatx4){0.f, 0.f, 0.f, 0.f};
    }

  for (int k0 = 0; k0 < DIM; k0 += 64) {
    __syncthreads();
#pragma unroll
    for (int b = 0; b < 2; b++) {
      int kk = k0 + b * 32;
      async16(gA0 + kk, As[b] + (wave * 2 + 0) * 512);
      async16(gA1 + kk, As[b] + (wave * 2 + 1) * 512);
      async16(gBi + kk, Bi[b] + wave * 512);
      async16(gBg + kk, Bg[b] + wave * 512);
    }
    __syncthreads();

#pragma unroll
    for (int b = 0; b < 2; b++) {
      short8 a[4];
#pragma unroll
      for (int i = 0; i < 4; i++)
        a[i] = *(const short8*)&As[b][(wm + i * 16 + lane16) * 32 + quad * 8];
#pragma unroll
      for (int j = 0; j < 2; j++) {
        short8 bi = *(const short8*)&Bi[b][(wn + j * 16 + lane16) * 32 + quad * 8];
#pragma unroll
        for (int i = 0; i < 4; i++)
          acc_i[i][j] = __builtin_amdgcn_mfma_f32_16x16x32_bf16(a[i], bi, acc_i[i][j], 0, 0, 0);
        short8 bg = *(const short8*)&Bg[b][(wn + j * 16 + lane16) * 32 + quad * 8];
#pragma unroll
        for (int i = 0; i < 4; i++)
          acc_g[i][j] = __builtin_amdgcn_mfma_f32_16x16x32_bf16(a[i], bg, acc_g[i][j], 0, 0, 0);
      }
    }
  }

  unsigned short* He = H + (size_t)e * CAP * IDIM;
#pragma unroll
  for (int i = 0; i < 4; i++) {
#pragma unroll
    for (int r = 0; r < 4; r++) {
      int m = m0 + wm + i * 16 + quad * 4 + r;
#pragma unroll
      for (int j = 0; j < 2; j++) {
        int n = i0 + wn + j * 16 + lane16;
        float vi = acc_i[i][j][r];
        float vg = acc_g[i][j][r];
        float h = 0.5f * vi * (1.0f + erff(vi * 0.70710678118654752f)) * vg;
        He[(size_t)m * IDIM + n] = f2b(h);
      }
    }
  }
}

// ---------------- GEMM2: full-K 128x128, gated scatter to out2[tok][slot] ----------------
__global__ __launch_bounds__(256, 4) void gemm2_kernel(const unsigned short* __restrict__ H,
                                                       const unsigned short* __restrict__ w2t,
                                                       const int* __restrict__ cnt,
                                                       const int* __restrict__ rowtok,
                                                       const int* __restrict__ rowslot,
                                                       const float* __restrict__ rowgate,
                                                       float* __restrict__ out2) {
  int e  = blockIdx.z;
  int m0 = blockIdx.y * 128;
  int n0 = blockIdx.x * 128;
  int cnte = cnt[e];
  if (m0 >= cnte) return;

  __shared__ __align__(16) unsigned char smem[32768];
  unsigned short* As[2] = { (unsigned short*)smem,           (unsigned short*)(smem + 8192) };
  unsigned short* Bs[2] = { (unsigned short*)(smem + 16384), (unsigned short*)(smem + 24576) };

  int tid  = threadIdx.x;
  int lane = tid & 63;
  int wave = tid >> 6;

  int sr0 = wave * 32 + (lane >> 2);
  int sr1 = sr0 + 16;
  int sk  = (lane & 3) * 8;

  const unsigned short* He  = H + (size_t)e * CAP * IDIM;
  const unsigned short* w2e = w2t + (size_t)e * DIM * IDIM;
  const unsigned short* gA0 = He + (size_t)(m0 + sr0) * IDIM + sk;
  const unsigned short* gA1 = He + (size_t)(m0 + sr1) * IDIM + sk;
  const unsigned short* gB0 = w2e + (size_t)(n0 + sr0) * IDIM + sk;
  const unsigned short* gB1 = w2e + (size_t)(n0 + sr1) * IDIM + sk;

  int lane16 = lane & 15;
  int quad   = lane >> 4;
  int wm = (wave & 1) * 64;
  int wn = (wave >> 1) * 64;

  floatx4 acc[4][4];
#pragma unroll
  for (int i = 0; i < 4; i++)
#pragma unroll
    for (int j = 0; j < 4; j++) acc[i][j] = (floatx4){0.f, 0.f, 0.f, 0.f};

  for (int k0 = 0; k0 < IDIM; k0 += 64) {
    __syncthreads();
#pragma unroll
    for (int b = 0; b < 2; b++) {
      int kk = k0 + b * 32;
      async16(gA0 + kk, As[b] + (wave * 2 + 0) * 512);
      async16(gA1 + kk, As[b] + (wave * 2 + 1) * 512);
      async16(gB0 + kk, Bs[b] + (wave * 2 + 0) * 512);
      async16(gB1 + kk, Bs[b] + (wave * 2 + 1) * 512);
    }
    __syncthreads();

#pragma unroll
    for (int b = 0; b < 2; b++) {
      short8 a[4];
#pragma unroll
      for (int i = 0; i < 4; i++)
        a[i] = *(const short8*)&As[b][(wm + i * 16 + lane16) * 32 + quad * 8];
#pragma unroll
      for (int j = 0; j < 4; j++) {
        short8 bb = *(const short8*)&Bs[b][(wn + j * 16 + lane16) * 32 + quad * 8];
#pragma unroll
        for (int i = 0; i < 4; i++)
          acc[i][j] = __builtin_amdgcn_mfma_f32_16x16x32_bf16(a[i], bb, acc[i][j], 0, 0, 0);
      }
    }
  }

#pragma unroll
  for (int i = 0; i < 4; i++) {
#pragma unroll
    for (int r = 0; r < 4; r++) {
      int m = m0 + wm + i * 16 + quad * 4 + r;
      if (m < cnte) {
        int tok = rowtok[e * CAP + m];
        int sl  = rowslot[e * CAP + m];
        float g = rowgate[e * CAP + m];
        float* orow = out2 + ((size_t)tok * 2 + sl) * DIM;
#pragma unroll
        for (int j = 0; j < 4; j++) {
          int n = n0 + wn + j * 16 + lane16;
          orow[n] = g * acc[i][j][r];
        }
      }
    }
  }
}

// ---------------- combine: out[t] = sel(g0)*out2[t][0] + sel(g1)*out2[t][1] ----------------
__global__ __launch_bounds__(256) void combine_kernel(const float* __restrict__ tokgate,
                                                      const float* __restrict__ out2,
                                                      float* __restrict__ out) {
  int t = blockIdx.x;
  int tid = threadIdx.x;
  float g0 = tokgate[t * 2], g1 = tokgate[t * 2 + 1];
  const float4* r0 = reinterpret_cast<const float4*>(out2 + (size_t)(t * 2) * DIM);
  const float4* r1 = reinterpret_cast<const float4*>(out2 + (size_t)(t * 2 + 1) * DIM);
  float4 a = r0[tid], b = r1[tid];   // poison rows are finite; selected away below
  float4 o;
  o.x = (g0 != 0.0f ? a.x : 0.0f) + (g1 != 0.0f ? b.x : 0.0f);
  o.y = (g0 != 0.0f ? a.y : 0.0f) + (g1 != 0.0f ? b.y : 0.0f);
  o.z = (g0 != 0.0f ? a.z : 0.0f) + (g1 != 0.0f ? b.z : 0.0f);
  o.w = (g0 != 0.0f ? a.w : 0.0f) + (g1 != 0.0f ? b.w : 0.0f);
  reinterpret_cast<float4*>(out + (size_t)t * DIM)[tid] = o;
}

// ---------------- launch ----------------
extern "C" void kernel_launch(void* const* d_in, const int* in_sizes, int n_in,
                              void* d_out, int out_size, void* d_ws, size_t ws_size,
                              hipStream_t stream) {
  const float* x  = (const float*)d_in[0];
  const float* Wg = (const float*)d_in[1];
  const float* W1 = (const float*)d_in[2];
  const float* W2 = (const float*)d_in[3];
  float* out = (float*)d_out;

  char* ws = (char*)d_ws;
  size_t off = 0;
  auto alloc = [&](size_t bytes) -> void* {
    void* p = ws + off;
    off = (off + bytes + 255) & ~(size_t)255;
    return p;
  };
  int*   top_i   = (int*)alloc((size_t)N_TOK * 2 * sizeof(int));
  float* gates   = (float*)alloc((size_t)N_TOK * 2 * sizeof(float));
  int*   rowtok  = (int*)alloc((size_t)NEXP * CAP * sizeof(int));
  int*   rowslot = (int*)alloc((size_t)NEXP * CAP * sizeof(int));
  float* rowgate = (float*)alloc((size_t)NEXP * CAP * sizeof(float));
  float* tokgate = (float*)alloc((size_t)N_TOK * 2 * sizeof(float));
  int*   cnt     = (int*)alloc((size_t)NEXP * sizeof(int));
  unsigned short* xb  = (unsigned short*)alloc((size_t)N_TOK * DIM * 2);
  unsigned short* w1t = (unsigned short*)alloc((size_t)NEXP * TWOI * DIM * 2);
  unsigned short* w2t = (unsigned short*)alloc((size_t)NEXP * DIM * IDIM * 2);
  unsigned short* Hb  = (unsigned short*)alloc((size_t)NEXP * CAP * IDIM * 2);
  float* out2 = (float*)alloc((size_t)N_TOK * 2 * DIM * sizeof(float));
  if (off > ws_size) return;

  hipLaunchKernelGGL(prologue_kernel, dim3(W1_BLOCKS + ROUTER_BLOCKS), dim3(256), 0, stream,
                     W1, w1t, x, Wg, xb, top_i, gates);
  hipLaunchKernelGGL(scan_kernel, dim3(1), dim3(1024), 0, stream,
                     top_i, gates, rowtok, rowslot, rowgate, tokgate, cnt);
  hipLaunchKernelGGL(gemm1_kernel, dim3(G1X, G1Y, NEXP + G1_TRANS_Z), dim3(256), 0, stream,
                     xb, w1t, rowtok, cnt, Hb, W2, w2t);
  hipLaunchKernelGGL(gemm2_kernel, dim3(DIM / 128, CAP / 128, NEXP), dim3(256), 0, stream,
                     Hb, w2t, cnt, rowtok, rowslot, rowgate, out2);
  hipLaunchKernelGGL(combine_kernel, dim3(N_TOK), dim3(256), 0, stream,
                     tokgate, out2, out);
}